// Round 3
// baseline (599.592 us; speedup 1.0000x reference)
//
#include <hip/hip_runtime.h>
#include <hip/hip_cooperative_groups.h>
#include <math.h>

namespace cg = cooperative_groups;

#define N_NODES 4096
#define E_EDGES 131072
#define EL_TOTAL (E_EDGES + N_NODES)
#define NEG_SLOPE 0.2f
#define NBLK 512
#define NTHR 256

// order-preserving float->uint encoding (for packed 64-bit argmax keys)
__device__ __forceinline__ unsigned enc_f(float f) {
    unsigned u = __float_as_uint(f);
    return (u & 0x80000000u) ? ~u : (u | 0x80000000u);
}
__device__ __forceinline__ float lrelu(float x) {
    return x >= 0.0f ? x : NEG_SLOPE * x;
}

struct Params {
    const float* x; const int* ei;
    const float* W1; const float* as1; const float* ad1; const float* b1;
    const float* W2; const float* as2; const float* ad2; const float* b2;
    const float* W3; const float* as3; const float* ad3; const float* b3;
    const float* phi1; const float* phi2;
    float* out;
    float* acc1; float* ssum1; float* acc2; float* ssum2;
    float* acc3; float* ssum3; float* x3buf; float* xfbuf;
    unsigned long long* nextkey; float* scal;
};

// h = relu(acc/(ssum+eps) + b) for one node (3-wide)
__device__ __forceinline__ void node_h3(const float* __restrict__ acc,
                                        const float* __restrict__ ssum,
                                        const float b0, const float b1, const float b2,
                                        int i, float h[3]) {
    float inv = 1.0f / (ssum[i] + 1e-16f);
    float v0 = acc[i * 3 + 0] * inv + b0; h[0] = v0 > 0.0f ? v0 : 0.0f;
    float v1 = acc[i * 3 + 1] * inv + b1; h[1] = v1 > 0.0f ? v1 : 0.0f;
    float v2 = acc[i * 3 + 2] * inv + b2; h[2] = v2 > 0.0f ? v2 : 0.0f;
}

__global__ __launch_bounds__(NTHR) void k_all(Params p) {
    cg::grid_group grid = cg::this_grid();
    const int t = threadIdx.x;
    const int gtid = blockIdx.x * NTHR + t;
    const int nthr = NBLK * NTHR;

    __shared__ int A[N_NODES];
    __shared__ int B[N_NODES];
    __shared__ float red[NTHR];
    __shared__ int redi[NTHR];

    // ---- P0: zero all accumulators (acc1..nextkey contiguous = 14N floats); block 0: scal + p12
    {
        float* zb = p.acc1;
        for (int i = gtid; i < 14 * N_NODES; i += nthr) zb[i] = 0.0f;
        if (blockIdx.x == 0) {
            if (t < 16) p.scal[t] = 0.0f;
            float pv = (t < 128) ? p.phi1[t] * p.phi2[t] : 0.0f;
            red[t] = pv; __syncthreads();
            for (int o = 128; o > 0; o >>= 1) { if (t < o) red[t] += red[t + o]; __syncthreads(); }
            if (t == 0) p.scal[0] = red[0];
        }
    }
    grid.sync();

    // ---- P1: layer-1 edges (h = x, z = x*W1)
    {
        float w0 = p.W1[0], w1 = p.W1[1], w2 = p.W1[2];
        float cs = w0 * p.as1[0] + w1 * p.as1[1] + w2 * p.as1[2];
        float cd = w0 * p.ad1[0] + w1 * p.ad1[1] + w2 * p.ad1[2];
        for (int j = gtid; j < EL_TOTAL; j += nthr) {
            int s, d;
            if (j < E_EDGES) { s = p.ei[j]; d = p.ei[E_EDGES + j]; }
            else             { s = j - E_EDGES; d = s; }
            float xs = p.x[s], xd = p.x[d];
            float w = expf(lrelu(xs * cs + xd * cd));
            atomicAdd(&p.ssum1[d], w);
            atomicAdd(&p.acc1[d * 3 + 0], w * (xs * w0));
            atomicAdd(&p.acc1[d * 3 + 1], w * (xs * w1));
            atomicAdd(&p.acc1[d * 3 + 2], w * (xs * w2));
        }
    }
    grid.sync();

    // ---- P2: layer-2 edges (h = relu(agg1+b1), z = h@W2^T, 3->3)
    {
        float W[9];
#pragma unroll
        for (int k = 0; k < 9; ++k) W[k] = p.W2[k];
        float as0 = p.as2[0], as1v = p.as2[1], as2v = p.as2[2];
        float ad0 = p.ad2[0], ad1v = p.ad2[1], ad2v = p.ad2[2];
        float b0 = p.b1[0], b1v = p.b1[1], b2v = p.b1[2];
        for (int j = gtid; j < EL_TOTAL; j += nthr) {
            int s, d;
            if (j < E_EDGES) { s = p.ei[j]; d = p.ei[E_EDGES + j]; }
            else             { s = j - E_EDGES; d = s; }
            float hs[3], hd[3];
            node_h3(p.acc1, p.ssum1, b0, b1v, b2v, s, hs);
            node_h3(p.acc1, p.ssum1, b0, b1v, b2v, d, hd);
            float zs0 = hs[0] * W[0] + hs[1] * W[1] + hs[2] * W[2];
            float zs1 = hs[0] * W[3] + hs[1] * W[4] + hs[2] * W[5];
            float zs2 = hs[0] * W[6] + hs[1] * W[7] + hs[2] * W[8];
            float zd0 = hd[0] * W[0] + hd[1] * W[1] + hd[2] * W[2];
            float zd1 = hd[0] * W[3] + hd[1] * W[4] + hd[2] * W[5];
            float zd2 = hd[0] * W[6] + hd[1] * W[7] + hd[2] * W[8];
            float es = zs0 * as0 + zs1 * as1v + zs2 * as2v;
            float ed = zd0 * ad0 + zd1 * ad1v + zd2 * ad2v;
            float w = expf(lrelu(es + ed));
            atomicAdd(&p.ssum2[d], w);
            atomicAdd(&p.acc2[d * 3 + 0], w * zs0);
            atomicAdd(&p.acc2[d * 3 + 1], w * zs1);
            atomicAdd(&p.acc2[d * 3 + 2], w * zs2);
        }
    }
    grid.sync();

    // ---- P3: layer-3 edges (h = relu(agg2+b2), z = h@W3^T, 3->1)
    {
        float w0 = p.W3[0], w1 = p.W3[1], w2 = p.W3[2];
        float asv = p.as3[0], adv = p.ad3[0];
        float b0 = p.b2[0], b1v = p.b2[1], b2v = p.b2[2];
        for (int j = gtid; j < EL_TOTAL; j += nthr) {
            int s, d;
            if (j < E_EDGES) { s = p.ei[j]; d = p.ei[E_EDGES + j]; }
            else             { s = j - E_EDGES; d = s; }
            float hs[3], hd[3];
            node_h3(p.acc2, p.ssum2, b0, b1v, b2v, s, hs);
            node_h3(p.acc2, p.ssum2, b0, b1v, b2v, d, hd);
            float zsv = hs[0] * w0 + hs[1] * w1 + hs[2] * w2;
            float zdv = hd[0] * w0 + hd[1] * w1 + hd[2] * w2;
            float w = expf(lrelu(zsv * asv + zdv * adv));
            atomicAdd(&p.ssum3[d], w);
            atomicAdd(&p.acc3[d], w * zsv);
        }
    }
    grid.sync();

    // ---- P4: x3 = agg3 + b3; S = sum(exp(x3)) via block-reduce + atomic
    {
        float b3v = p.b3[0];
        float ls = 0.0f;
        for (int i = gtid; i < N_NODES; i += nthr) {
            float v = p.acc3[i] / (p.ssum3[i] + 1e-16f) + b3v;
            p.x3buf[i] = v;
            ls += expf(v);
        }
        red[t] = ls; __syncthreads();
        for (int o = 128; o > 0; o >>= 1) { if (t < o) red[t] += red[t + o]; __syncthreads(); }
        if (t == 0) atomicAdd(&p.scal[1], red[0]);
    }
    grid.sync();

    // ---- P5: softmax write + argmax(xf) (packed key, first-index tie-break)
    {
        float S = p.scal[1];
        float bv = -INFINITY; int bi = 0x7fffffff;
        for (int i = gtid; i < N_NODES; i += nthr) {
            float v = expf(p.x3buf[i]) / S;
            p.out[i] = v;
            p.xfbuf[i] = v;
            if (v > bv) { bv = v; bi = i; }   // i strictly increasing per thread
        }
        red[t] = bv; redi[t] = bi; __syncthreads();
        for (int o = 128; o > 0; o >>= 1) {
            if (t < o) {
                float v2 = red[t + o]; int i2 = redi[t + o];
                if (v2 > red[t] || (v2 == red[t] && i2 < redi[t])) { red[t] = v2; redi[t] = i2; }
            }
            __syncthreads();
        }
        if (t == 0) {
            unsigned long long key = ((unsigned long long)enc_f(red[0]) << 32)
                                   | (unsigned long long)(~(unsigned)redi[0]);
            atomicMax((unsigned long long*)(p.scal + 2), key);
        }
    }
    grid.sync();

    // ---- P6: chain edges — per-src argmax of tanh score over original edges
    {
        float p12 = p.scal[0];
        const float scale = 1.0f / 11.313708498984761f;   // 1/sqrt(128) in fp32
        for (int j = gtid; j < E_EDGES; j += nthr) {
            int s = p.ei[j], d = p.ei[E_EDGES + j];
            float sc = tanhf(((p12 * p.xfbuf[s]) * p.xfbuf[d]) * scale);
            unsigned long long key = ((unsigned long long)enc_f(sc) << 32)
                                   | (unsigned long long)(~(unsigned)j);
            atomicMax(&p.nextkey[s], key);
        }
    }
    grid.sync();

    // ---- P7: block 0 — binary lifting next^4096, write final
    if (blockIdx.x == 0) {
        int d0 = p.ei[E_EDGES];   // all-(-inf) argmax -> edge 0 -> dst0[0]
        for (int i = t; i < N_NODES; i += NTHR) {
            unsigned long long key = p.nextkey[i];
            int nxt;
            if (key == 0ull) nxt = d0;
            else {
                unsigned j = ~(unsigned)(key & 0xFFFFFFFFull);
                nxt = p.ei[E_EDGES + j];
            }
            A[i] = nxt;
        }
        __syncthreads();
        for (int r = 0; r < 12; ++r) {   // 2^12 = 4096 steps
            for (int i = t; i < N_NODES; i += NTHR) B[i] = A[A[i]];
            __syncthreads();
            for (int i = t; i < N_NODES; i += NTHR) A[i] = B[i];
            __syncthreads();
        }
        if (t == 0) {
            unsigned long long ak = *(unsigned long long*)(p.scal + 2);
            int start = (int)~(unsigned)(ak & 0xFFFFFFFFull);
            p.out[N_NODES] = (float)A[start];
        }
    }
}

// ---------- launch ----------

extern "C" void kernel_launch(void* const* d_in, const int* in_sizes, int n_in,
                              void* d_out, int out_size, void* d_ws, size_t ws_size,
                              hipStream_t stream) {
    Params p;
    p.x    = (const float*)d_in[0];
    p.ei   = (const int*)  d_in[1];
    p.W1   = (const float*)d_in[2];
    p.as1  = (const float*)d_in[3];
    p.ad1  = (const float*)d_in[4];
    p.b1   = (const float*)d_in[5];
    p.W2   = (const float*)d_in[6];
    p.as2  = (const float*)d_in[7];
    p.ad2  = (const float*)d_in[8];
    p.b2   = (const float*)d_in[9];
    p.W3   = (const float*)d_in[10];
    p.as3  = (const float*)d_in[11];
    p.ad3  = (const float*)d_in[12];
    p.b3   = (const float*)d_in[13];
    p.phi1 = (const float*)d_in[14];
    p.phi2 = (const float*)d_in[15];
    p.out  = (float*)d_out;

    float* ws = (float*)d_ws;
    p.acc1  = ws;                       // 3N   -- start of contiguous zero range (14N floats)
    p.ssum1 = p.acc1 + 3 * N_NODES;     // N
    p.acc2  = p.ssum1 + N_NODES;        // 3N
    p.ssum2 = p.acc2 + 3 * N_NODES;     // N
    p.acc3  = p.ssum2 + N_NODES;        // N
    p.ssum3 = p.acc3 + N_NODES;         // N
    p.x3buf = p.ssum3 + N_NODES;        // N
    p.xfbuf = p.x3buf + N_NODES;        // N
    p.nextkey = (unsigned long long*)(p.xfbuf + N_NODES);  // 2N floats, 8B-aligned
    p.scal  = (float*)(p.nextkey + N_NODES);               // 16 floats

    void* args[] = { &p };
    hipLaunchCooperativeKernel((void*)k_all, dim3(NBLK), dim3(NTHR), args, 0, stream);
}

// Round 4
// 256.489 us; speedup vs baseline: 2.3377x; 2.3377x over previous
//
#include <hip/hip_runtime.h>
#include <math.h>

#define N_NODES 4096
#define E_EDGES 131072
#define EL_TOTAL (E_EDGES + N_NODES)
#define NEG_SLOPE 0.2f
#define NBLK 256
#define NTHR 256
#define NTOT (NBLK * NTHR)

#define SCOPE_A __HIP_MEMORY_SCOPE_AGENT
#define RLX __ATOMIC_RELAXED

// ---------- coherent (coherence-point) access helpers ----------
__device__ __forceinline__ float aload(const float* p) {
    return __hip_atomic_load(p, RLX, SCOPE_A);
}
__device__ __forceinline__ void astore(float* p, float v) {
    __hip_atomic_store(p, v, RLX, SCOPE_A);
}
__device__ __forceinline__ unsigned long long aload_u64(const unsigned long long* p) {
    return __hip_atomic_load(p, RLX, SCOPE_A);
}
__device__ __forceinline__ void astore_u64(unsigned long long* p, unsigned long long v) {
    __hip_atomic_store(p, v, RLX, SCOPE_A);
}
__device__ __forceinline__ void aadd(float* p, float v) {
    __hip_atomic_fetch_add(p, v, RLX, SCOPE_A);
}
__device__ __forceinline__ void amax_u64(unsigned long long* p, unsigned long long v) {
    __hip_atomic_fetch_max(p, v, RLX, SCOPE_A);
}

// order-preserving float->uint encoding (for packed 64-bit argmax keys)
__device__ __forceinline__ unsigned enc_f(float f) {
    unsigned u = __float_as_uint(f);
    return (u & 0x80000000u) ? ~u : (u | 0x80000000u);
}
__device__ __forceinline__ float lrelu(float x) {
    return x >= 0.0f ? x : NEG_SLOPE * x;
}

// Relaxed grid barrier: no cache maintenance. Correct because ALL cross-phase
// data moves through device-scope atomics (coherence point); __syncthreads()
// drains each wave's vmcnt so every prior atomic is complete at the point of
// the arrival increment.
__device__ __forceinline__ void gbar(unsigned* ctr, unsigned target) {
    __syncthreads();
    if (threadIdx.x == 0) {
        __builtin_amdgcn_s_waitcnt(0);
        __hip_atomic_fetch_add(ctr, 1u, RLX, SCOPE_A);
        while (__hip_atomic_load(ctr, RLX, SCOPE_A) < target)
            __builtin_amdgcn_s_sleep(2);
    }
    __syncthreads();
}

struct Params {
    const float* x; const int* ei;
    const float* W1; const float* as1; const float* ad1; const float* b1;
    const float* W2; const float* as2; const float* ad2; const float* b2;
    const float* W3; const float* as3; const float* ad3; const float* b3;
    const float* phi1; const float* phi2;
    float* out;
    float* acc1; float* ssum1; float* acc2; float* ssum2;
    float* acc3; float* ssum3; float* x3buf; float* xfbuf;
    unsigned long long* nextkey;
    float* scal;        // [0]=p12, [1]=S, [2:3]=argmax key (ull)
    unsigned* ctr;      // barrier counter (zeroed by memsetAsync)
};

// h = relu(acc/(ssum+eps) + b) for one node (3-wide), via coherent loads
__device__ __forceinline__ void node_h3(const float* __restrict__ acc,
                                        const float* __restrict__ ssum,
                                        float b0, float b1, float b2,
                                        int i, float h[3]) {
    float inv = 1.0f / (aload(&ssum[i]) + 1e-16f);
    float v0 = aload(&acc[i * 3 + 0]) * inv + b0; h[0] = v0 > 0.0f ? v0 : 0.0f;
    float v1 = aload(&acc[i * 3 + 1]) * inv + b1; h[1] = v1 > 0.0f ? v1 : 0.0f;
    float v2 = aload(&acc[i * 3 + 2]) * inv + b2; h[2] = v2 > 0.0f ? v2 : 0.0f;
}

__global__ __launch_bounds__(NTHR) void k_fused(Params p) {
    const int t = threadIdx.x;
    const int gtid = blockIdx.x * NTHR + t;

    __shared__ int A[N_NODES];
    __shared__ int B[N_NODES];
    __shared__ float red[NTHR];
    __shared__ int redi[NTHR];

    // ---- P0: zero accumulators + nextkey (coherent stores); block 0: p12
    {
        for (int i = gtid; i < 10 * N_NODES; i += NTOT) astore(&p.acc1[i], 0.0f);
        for (int i = gtid; i < N_NODES; i += NTOT) astore_u64(&p.nextkey[i], 0ull);
        if (blockIdx.x == 0) {
            float pv = (t < 128) ? p.phi1[t] * p.phi2[t] : 0.0f;
            red[t] = pv; __syncthreads();
            for (int o = 128; o > 0; o >>= 1) { if (t < o) red[t] += red[t + o]; __syncthreads(); }
            if (t == 0) astore(&p.scal[0], red[0]);
        }
    }
    gbar(p.ctr, 1 * NBLK);

    // ---- P1: layer-1 edges (h = x, z = x*W1)
    {
        float w0 = p.W1[0], w1 = p.W1[1], w2 = p.W1[2];
        float cs = w0 * p.as1[0] + w1 * p.as1[1] + w2 * p.as1[2];
        float cd = w0 * p.ad1[0] + w1 * p.ad1[1] + w2 * p.ad1[2];
        for (int j = gtid; j < EL_TOTAL; j += NTOT) {
            int s, d;
            if (j < E_EDGES) { s = p.ei[j]; d = p.ei[E_EDGES + j]; }
            else             { s = j - E_EDGES; d = s; }
            float xs = p.x[s], xd = p.x[d];
            float w = expf(lrelu(xs * cs + xd * cd));
            aadd(&p.ssum1[d], w);
            aadd(&p.acc1[d * 3 + 0], w * (xs * w0));
            aadd(&p.acc1[d * 3 + 1], w * (xs * w1));
            aadd(&p.acc1[d * 3 + 2], w * (xs * w2));
        }
    }
    gbar(p.ctr, 2 * NBLK);

    // ---- P2: layer-2 edges (h = relu(agg1+b1), z = h@W2^T, 3->3)
    {
        float W[9];
#pragma unroll
        for (int k = 0; k < 9; ++k) W[k] = p.W2[k];
        float as0 = p.as2[0], as1v = p.as2[1], as2v = p.as2[2];
        float ad0 = p.ad2[0], ad1v = p.ad2[1], ad2v = p.ad2[2];
        float b0 = p.b1[0], b1v = p.b1[1], b2v = p.b1[2];
        for (int j = gtid; j < EL_TOTAL; j += NTOT) {
            int s, d;
            if (j < E_EDGES) { s = p.ei[j]; d = p.ei[E_EDGES + j]; }
            else             { s = j - E_EDGES; d = s; }
            float hs[3], hd[3];
            node_h3(p.acc1, p.ssum1, b0, b1v, b2v, s, hs);
            node_h3(p.acc1, p.ssum1, b0, b1v, b2v, d, hd);
            float zs0 = hs[0] * W[0] + hs[1] * W[1] + hs[2] * W[2];
            float zs1 = hs[0] * W[3] + hs[1] * W[4] + hs[2] * W[5];
            float zs2 = hs[0] * W[6] + hs[1] * W[7] + hs[2] * W[8];
            float zd0 = hd[0] * W[0] + hd[1] * W[1] + hd[2] * W[2];
            float zd1 = hd[0] * W[3] + hd[1] * W[4] + hd[2] * W[5];
            float zd2 = hd[0] * W[6] + hd[1] * W[7] + hd[2] * W[8];
            float es = zs0 * as0 + zs1 * as1v + zs2 * as2v;
            float ed = zd0 * ad0 + zd1 * ad1v + zd2 * ad2v;
            float w = expf(lrelu(es + ed));
            aadd(&p.ssum2[d], w);
            aadd(&p.acc2[d * 3 + 0], w * zs0);
            aadd(&p.acc2[d * 3 + 1], w * zs1);
            aadd(&p.acc2[d * 3 + 2], w * zs2);
        }
    }
    gbar(p.ctr, 3 * NBLK);

    // ---- P3: layer-3 edges (h = relu(agg2+b2), z = h@W3^T, 3->1)
    {
        float w0 = p.W3[0], w1 = p.W3[1], w2 = p.W3[2];
        float asv = p.as3[0], adv = p.ad3[0];
        float b0 = p.b2[0], b1v = p.b2[1], b2v = p.b2[2];
        for (int j = gtid; j < EL_TOTAL; j += NTOT) {
            int s, d;
            if (j < E_EDGES) { s = p.ei[j]; d = p.ei[E_EDGES + j]; }
            else             { s = j - E_EDGES; d = s; }
            float hs[3], hd[3];
            node_h3(p.acc2, p.ssum2, b0, b1v, b2v, s, hs);
            node_h3(p.acc2, p.ssum2, b0, b1v, b2v, d, hd);
            float zsv = hs[0] * w0 + hs[1] * w1 + hs[2] * w2;
            float zdv = hd[0] * w0 + hd[1] * w1 + hd[2] * w2;
            float w = expf(lrelu(zsv * asv + zdv * adv));
            aadd(&p.ssum3[d], w);
            aadd(&p.acc3[d], w * zsv);
        }
    }
    gbar(p.ctr, 4 * NBLK);

    // ---- P4: x3 = agg3 + b3; S = sum(exp(x3))
    {
        float b3v = p.b3[0];
        float ls = 0.0f;
        for (int i = gtid; i < N_NODES; i += NTOT) {
            float v = aload(&p.acc3[i]) / (aload(&p.ssum3[i]) + 1e-16f) + b3v;
            astore(&p.x3buf[i], v);
            ls += expf(v);
        }
        red[t] = ls; __syncthreads();
        for (int o = 128; o > 0; o >>= 1) { if (t < o) red[t] += red[t + o]; __syncthreads(); }
        if (t == 0) aadd(&p.scal[1], red[0]);
    }
    gbar(p.ctr, 5 * NBLK);

    // ---- P5: softmax write + global argmax(xf) (packed key, first-index ties)
    {
        float S = aload(&p.scal[1]);
        float bv = -INFINITY; int bi = 0x7fffffff;
        for (int i = gtid; i < N_NODES; i += NTOT) {
            float v = expf(aload(&p.x3buf[i])) / S;
            p.out[i] = v;
            astore(&p.xfbuf[i], v);
            if (v > bv) { bv = v; bi = i; }   // i strictly increasing per thread
        }
        red[t] = bv; redi[t] = bi; __syncthreads();
        for (int o = 128; o > 0; o >>= 1) {
            if (t < o) {
                float v2 = red[t + o]; int i2 = redi[t + o];
                if (v2 > red[t] || (v2 == red[t] && i2 < redi[t])) { red[t] = v2; redi[t] = i2; }
            }
            __syncthreads();
        }
        if (t == 0) {
            unsigned long long key = ((unsigned long long)enc_f(red[0]) << 32)
                                   | (unsigned long long)(~(unsigned)redi[0]);
            amax_u64((unsigned long long*)(p.scal + 2), key);
        }
    }
    gbar(p.ctr, 6 * NBLK);

    // ---- P6: chain edges — per-src argmax of tanh score over original edges
    {
        float p12 = aload(&p.scal[0]);
        const float scale = 1.0f / 11.313708498984761f;   // 1/sqrt(128)
        for (int j = gtid; j < E_EDGES; j += NTOT) {
            int s = p.ei[j], d = p.ei[E_EDGES + j];
            float xfs = aload(&p.xfbuf[s]);
            float xfd = aload(&p.xfbuf[d]);
            float sc = tanhf(((p12 * xfs) * xfd) * scale);
            unsigned long long key = ((unsigned long long)enc_f(sc) << 32)
                                   | (unsigned long long)(~(unsigned)j);
            amax_u64(&p.nextkey[s], key);
        }
    }
    gbar(p.ctr, 7 * NBLK);

    // ---- P7: block 0 — binary lifting next^4096, write final
    if (blockIdx.x == 0) {
        int d0 = p.ei[E_EDGES];   // all-(-inf) argmax -> edge 0 -> dst0[0]
        for (int i = t; i < N_NODES; i += NTHR) {
            unsigned long long key = aload_u64(&p.nextkey[i]);
            int nxt;
            if (key == 0ull) nxt = d0;
            else {
                unsigned j = ~(unsigned)(key & 0xFFFFFFFFull);
                nxt = p.ei[E_EDGES + j];
            }
            A[i] = nxt;
        }
        __syncthreads();
        for (int r = 0; r < 12; ++r) {   // 2^12 = 4096 steps
            for (int i = t; i < N_NODES; i += NTHR) B[i] = A[A[i]];
            __syncthreads();
            for (int i = t; i < N_NODES; i += NTHR) A[i] = B[i];
            __syncthreads();
        }
        if (t == 0) {
            unsigned long long ak = aload_u64((unsigned long long*)(p.scal + 2));
            int start = (int)~(unsigned)(ak & 0xFFFFFFFFull);
            p.out[N_NODES] = (float)A[start];
        }
    }
}

// ---------- launch ----------

extern "C" void kernel_launch(void* const* d_in, const int* in_sizes, int n_in,
                              void* d_out, int out_size, void* d_ws, size_t ws_size,
                              hipStream_t stream) {
    Params p;
    p.x    = (const float*)d_in[0];
    p.ei   = (const int*)  d_in[1];
    p.W1   = (const float*)d_in[2];
    p.as1  = (const float*)d_in[3];
    p.ad1  = (const float*)d_in[4];
    p.b1   = (const float*)d_in[5];
    p.W2   = (const float*)d_in[6];
    p.as2  = (const float*)d_in[7];
    p.ad2  = (const float*)d_in[8];
    p.b2   = (const float*)d_in[9];
    p.W3   = (const float*)d_in[10];
    p.as3  = (const float*)d_in[11];
    p.ad3  = (const float*)d_in[12];
    p.b3   = (const float*)d_in[13];
    p.phi1 = (const float*)d_in[14];
    p.phi2 = (const float*)d_in[15];
    p.out  = (float*)d_out;

    float* ws = (float*)d_ws;
    p.acc1  = ws;                       // 3N  -- start of 10N-float zero range
    p.ssum1 = p.acc1 + 3 * N_NODES;     // N
    p.acc2  = p.ssum1 + N_NODES;        // 3N
    p.ssum2 = p.acc2 + 3 * N_NODES;     // N
    p.acc3  = p.ssum2 + N_NODES;        // N
    p.ssum3 = p.acc3 + N_NODES;         // N
    p.x3buf = p.ssum3 + N_NODES;        // N   (written before read)
    p.xfbuf = p.x3buf + N_NODES;        // N   (written before read)
    p.nextkey = (unsigned long long*)(p.xfbuf + N_NODES);  // N ull (zeroed in P0)
    p.scal  = (float*)(p.nextkey + N_NODES);               // scalars
    p.ctr   = (unsigned*)(p.scal + 8);                     // barrier counter

    // zero the scalar/counter block only (cannot self-initialize the barrier
    // counter inside the kernel that uses it)
    hipMemsetAsync((void*)p.scal, 0, 256, stream);
    k_fused<<<dim3(NBLK), dim3(NTHR), 0, stream>>>(p);
}

// Round 5
// 228.772 us; speedup vs baseline: 2.6209x; 1.1212x over previous
//
#include <hip/hip_runtime.h>
#include <math.h>

#define N_NODES 4096
#define E_EDGES 131072
#define NEG_SLOPE 0.2f
#define NBLK 256
#define NTHR 1024
#define SLICE 16                 // N_NODES / NBLK

typedef unsigned long long u64;

#define SCOPE_A __HIP_MEMORY_SCOPE_AGENT
#define RLX __ATOMIC_RELAXED

// ---------- agent-scope (coherence-point) helpers ----------
__device__ __forceinline__ float aloadf(const float* p) {
    return __hip_atomic_load(p, RLX, SCOPE_A);
}
__device__ __forceinline__ void astoref(float* p, float v) {
    __hip_atomic_store(p, v, RLX, SCOPE_A);
}
__device__ __forceinline__ int aloadi(const int* p) {
    return __hip_atomic_load(p, RLX, SCOPE_A);
}
__device__ __forceinline__ void astorei(int* p, int v) {
    __hip_atomic_store(p, v, RLX, SCOPE_A);
}
__device__ __forceinline__ u64 ald64(const u64* p) {
    return __hip_atomic_load(p, RLX, SCOPE_A);
}
__device__ __forceinline__ void ast64(u64* p, u64 v) {
    __hip_atomic_store(p, v, RLX, SCOPE_A);
}
__device__ __forceinline__ void aaddf(float* p, float v) {
    __hip_atomic_fetch_add(p, v, RLX, SCOPE_A);
}
__device__ __forceinline__ void amax64(u64* p, u64 v) {
    __hip_atomic_fetch_max(p, v, RLX, SCOPE_A);
}

union F2U { float2 f; u64 u; };
__device__ __forceinline__ u64 packf2(float a, float b) {
    F2U x; x.f = make_float2(a, b); return x.u;
}
__device__ __forceinline__ float2 unpackf2(u64 v) { F2U x; x.u = v; return x.f; }

// order-preserving float->uint encoding (packed 64-bit argmax keys)
__device__ __forceinline__ unsigned enc_f(float f) {
    unsigned u = __float_as_uint(f);
    return (u & 0x80000000u) ? ~u : (u | 0x80000000u);
}
__device__ __forceinline__ float lrelu(float x) {
    return x >= 0.0f ? x : NEG_SLOPE * x;
}

// Relaxed grid barrier: no cache maintenance. All cross-block data moves via
// agent-scope ops (coherence point). Every wave drains its own counters before
// the LDS barrier; thread 0 then publishes arrival. (Pattern validated R4.)
__device__ __forceinline__ void gbar(unsigned* ctr, unsigned target) {
    __builtin_amdgcn_s_waitcnt(0);
    __syncthreads();
    if (threadIdx.x == 0) {
        __hip_atomic_fetch_add(ctr, 1u, RLX, SCOPE_A);
        while (__hip_atomic_load(ctr, RLX, SCOPE_A) < target)
            __builtin_amdgcn_s_sleep(2);
    }
    __syncthreads();
}

struct Params {
    const float* x; const int* ei;
    const float* W1; const float* as1; const float* ad1; const float* b1;
    const float* W2; const float* as2; const float* ad2; const float* b2;
    const float* W3; const float* as3; const float* ad3; const float* b3;
    const float* phi1; const float* phi2;
    float* out;
    u64* P2;        // per-node (es2, z20 | z21, z22)   2 u64 each
    u64* P3;        // per-node (es3, z3)               1 u64 each
    float* xf;      // per-node softmax value
    int* nxt;       // per-node chain successor
    float* scalS;   // softmax denominator accumulator
    u64* argkey;    // global argmax(xf) packed key
    unsigned* ctr;  // barrier counter
};

__global__ __launch_bounds__(NTHR) void k_gat(Params p) {
    const int t = threadIdx.x;
    const int b = blockIdx.x;
    const int base = b * SLICE;

    __shared__ float s_ssum[SLICE];
    __shared__ float s_acc[SLICE][3];
    __shared__ float s_ed[SLICE];       // dest-side attention dot for own nodes
    __shared__ float s_es[SLICE];       // src-side dot for own nodes (self-loops)
    __shared__ float s_z[SLICE][3];     // own z (self-loops)
    __shared__ float s_x3[SLICE];
    __shared__ float s_exp[SLICE];
    __shared__ float s_xf[SLICE];
    __shared__ u64   s_key[SLICE];
    __shared__ float s_phired[128];
    __shared__ float s_p12;
    __shared__ int A[N_NODES];          // lift tables (block 0)
    __shared__ int B[N_NODES];

    const int* srcA = p.ei;
    const int* dstA = p.ei + E_EDGES;
    const int4* src4 = (const int4*)srcA;
    const int4* dst4 = (const int4*)dstA;

    // ================= layer 1 (h = x) =================
    {
        float w0 = p.W1[0], w1 = p.W1[1], w2 = p.W1[2];
        float cs = w0 * p.as1[0] + w1 * p.as1[1] + w2 * p.as1[2];
        float cd = w0 * p.ad1[0] + w1 * p.ad1[1] + w2 * p.ad1[2];

        if (t < SLICE) {
            float xi = p.x[base + t];
            s_ed[t] = xi * cd;
            s_ssum[t] = 0.0f;
            s_acc[t][0] = 0.0f; s_acc[t][1] = 0.0f; s_acc[t][2] = 0.0f;
        }
        __syncthreads();

        if (t < SLICE) {               // self-loop for own node
            float xi = p.x[base + t];
            float w = expf(lrelu(xi * cs + s_ed[t]));
            atomicAdd(&s_ssum[t], w);
            atomicAdd(&s_acc[t][0], w * (xi * w0));
            atomicAdd(&s_acc[t][1], w * (xi * w1));
            atomicAdd(&s_acc[t][2], w * (xi * w2));
        }
        for (int q = t; q < E_EDGES / 4; q += NTHR) {
            int4 dv = dst4[q];
            int j0 = q * 4;
#define L1_PROC(dd, jj)                                              \
            if (((dd) >> 4) == b) {                                  \
                float xs = p.x[srcA[jj]];                            \
                int li = (dd) & 15;                                  \
                float w = expf(lrelu(xs * cs + s_ed[li]));           \
                atomicAdd(&s_ssum[li], w);                           \
                atomicAdd(&s_acc[li][0], w * (xs * w0));             \
                atomicAdd(&s_acc[li][1], w * (xs * w1));             \
                atomicAdd(&s_acc[li][2], w * (xs * w2));             \
            }
            L1_PROC(dv.x, j0 + 0)
            L1_PROC(dv.y, j0 + 1)
            L1_PROC(dv.z, j0 + 2)
            L1_PROC(dv.w, j0 + 3)
#undef L1_PROC
        }
        __syncthreads();

        if (t < SLICE) {               // epilogue: h1 -> publish P2, local ed2
            int i = base + t;
            float inv = 1.0f / (s_ssum[t] + 1e-16f);
            float h0 = s_acc[t][0] * inv + p.b1[0]; h0 = h0 > 0.0f ? h0 : 0.0f;
            float h1 = s_acc[t][1] * inv + p.b1[1]; h1 = h1 > 0.0f ? h1 : 0.0f;
            float h2 = s_acc[t][2] * inv + p.b1[2]; h2 = h2 > 0.0f ? h2 : 0.0f;
            float z0 = h0 * p.W2[0] + h1 * p.W2[1] + h2 * p.W2[2];
            float z1 = h0 * p.W2[3] + h1 * p.W2[4] + h2 * p.W2[5];
            float z2 = h0 * p.W2[6] + h1 * p.W2[7] + h2 * p.W2[8];
            float es2 = z0 * p.as2[0] + z1 * p.as2[1] + z2 * p.as2[2];
            float ed2 = z0 * p.ad2[0] + z1 * p.ad2[1] + z2 * p.ad2[2];
            ast64(&p.P2[i * 2 + 0], packf2(es2, z0));
            ast64(&p.P2[i * 2 + 1], packf2(z1, z2));
            s_es[t] = es2; s_ed[t] = ed2;
            s_z[t][0] = z0; s_z[t][1] = z1; s_z[t][2] = z2;
            s_ssum[t] = 0.0f;
            s_acc[t][0] = 0.0f; s_acc[t][1] = 0.0f; s_acc[t][2] = 0.0f;
        }
    }
    gbar(p.ctr, 1 * NBLK);

    // ================= layer 2 =================
    {
        if (t < SLICE) {               // self-loop
            float w = expf(lrelu(s_es[t] + s_ed[t]));
            atomicAdd(&s_ssum[t], w);
            atomicAdd(&s_acc[t][0], w * s_z[t][0]);
            atomicAdd(&s_acc[t][1], w * s_z[t][1]);
            atomicAdd(&s_acc[t][2], w * s_z[t][2]);
        }
        for (int q = t; q < E_EDGES / 4; q += NTHR) {
            int4 dv = dst4[q];
            int j0 = q * 4;
#define L2_PROC(dd, jj)                                              \
            if (((dd) >> 4) == b) {                                  \
                int s = srcA[jj];                                    \
                float2 f0 = unpackf2(ald64(&p.P2[s * 2 + 0]));       \
                float2 f1 = unpackf2(ald64(&p.P2[s * 2 + 1]));       \
                int li = (dd) & 15;                                  \
                float w = expf(lrelu(f0.x + s_ed[li]));              \
                atomicAdd(&s_ssum[li], w);                           \
                atomicAdd(&s_acc[li][0], w * f0.y);                  \
                atomicAdd(&s_acc[li][1], w * f1.x);                  \
                atomicAdd(&s_acc[li][2], w * f1.y);                  \
            }
            L2_PROC(dv.x, j0 + 0)
            L2_PROC(dv.y, j0 + 1)
            L2_PROC(dv.z, j0 + 2)
            L2_PROC(dv.w, j0 + 3)
#undef L2_PROC
        }
        __syncthreads();

        if (t < SLICE) {               // epilogue: h2 -> publish P3, local ed3
            int i = base + t;
            float inv = 1.0f / (s_ssum[t] + 1e-16f);
            float h0 = s_acc[t][0] * inv + p.b2[0]; h0 = h0 > 0.0f ? h0 : 0.0f;
            float h1 = s_acc[t][1] * inv + p.b2[1]; h1 = h1 > 0.0f ? h1 : 0.0f;
            float h2 = s_acc[t][2] * inv + p.b2[2]; h2 = h2 > 0.0f ? h2 : 0.0f;
            float z3 = h0 * p.W3[0] + h1 * p.W3[1] + h2 * p.W3[2];
            float es3 = z3 * p.as3[0];
            float ed3 = z3 * p.ad3[0];
            ast64(&p.P3[i], packf2(es3, z3));
            s_es[t] = es3; s_ed[t] = ed3; s_z[t][0] = z3;
            s_ssum[t] = 0.0f; s_acc[t][0] = 0.0f;
        }
    }
    gbar(p.ctr, 2 * NBLK);

    // ================= layer 3 + softmax denominator =================
    {
        if (t < SLICE) {               // self-loop
            float w = expf(lrelu(s_es[t] + s_ed[t]));
            atomicAdd(&s_ssum[t], w);
            atomicAdd(&s_acc[t][0], w * s_z[t][0]);
        }
        for (int q = t; q < E_EDGES / 4; q += NTHR) {
            int4 dv = dst4[q];
            int j0 = q * 4;
#define L3_PROC(dd, jj)                                              \
            if (((dd) >> 4) == b) {                                  \
                int s = srcA[jj];                                    \
                float2 f = unpackf2(ald64(&p.P3[s]));                \
                int li = (dd) & 15;                                  \
                float w = expf(lrelu(f.x + s_ed[li]));               \
                atomicAdd(&s_ssum[li], w);                           \
                atomicAdd(&s_acc[li][0], w * f.y);                   \
            }
            L3_PROC(dv.x, j0 + 0)
            L3_PROC(dv.y, j0 + 1)
            L3_PROC(dv.z, j0 + 2)
            L3_PROC(dv.w, j0 + 3)
#undef L3_PROC
        }
        __syncthreads();

        if (t < SLICE) {
            float x3 = s_acc[t][0] / (s_ssum[t] + 1e-16f) + p.b3[0];
            s_x3[t] = x3;
            s_exp[t] = expf(x3);
        }
        // p12 (block-local, overlapped with L3 epilogue)
        if (t < 128) s_phired[t] = p.phi1[t] * p.phi2[t];
        __syncthreads();
        if (t < 64) s_phired[t] += s_phired[t + 64];
        __syncthreads();
        if (t == 0) {
            float a = 0.0f;
            for (int k = 0; k < 64; ++k) a += s_phired[k];
            s_p12 = a;
            float part = 0.0f;
            for (int k = 0; k < SLICE; ++k) part += s_exp[k];
            aaddf(p.scalS, part);
        }
    }
    gbar(p.ctr, 3 * NBLK);

    // ================= softmax write + global argmax =================
    {
        float S = aloadf(p.scalS);
        if (t < SLICE) {
            float v = s_exp[t] / S;
            s_xf[t] = v;
            astoref(&p.xf[base + t], v);
            p.out[base + t] = v;
            s_key[t] = 0ull;
        }
        __syncthreads();
        if (t == 0) {
            float bv = -INFINITY; int bi = 0;
            for (int k = 0; k < SLICE; ++k) {
                float v = s_xf[k];
                if (v > bv) { bv = v; bi = base + k; }   // ascending k: first-index ties
            }
            u64 key = ((u64)enc_f(bv) << 32) | (u64)(~(unsigned)bi);
            amax64(p.argkey, key);
        }
    }
    gbar(p.ctr, 4 * NBLK);

    // ================= chain edges (partitioned by src) =================
    {
        float p12 = s_p12;
        const float scale = 1.0f / 11.313708498984761f;   // 1/sqrt(128)
        for (int q = t; q < E_EDGES / 4; q += NTHR) {
            int4 sv = src4[q];
            int j0 = q * 4;
#define CH_PROC(ss, jj)                                                      \
            if (((ss) >> 4) == b) {                                          \
                int d = dstA[jj];                                            \
                float xfd = aloadf(&p.xf[d]);                                \
                float sc = tanhf(((p12 * s_xf[(ss) & 15]) * xfd) * scale);   \
                u64 key = ((u64)enc_f(sc) << 32) | (u64)(~(unsigned)(jj));   \
                atomicMax(&s_key[(ss) & 15], key);                           \
            }
            CH_PROC(sv.x, j0 + 0)
            CH_PROC(sv.y, j0 + 1)
            CH_PROC(sv.z, j0 + 2)
            CH_PROC(sv.w, j0 + 3)
#undef CH_PROC
        }
        __syncthreads();
        if (t < SLICE) {
            u64 key = s_key[t];
            int nxt;
            if (key == 0ull) nxt = dstA[0];   // all -inf -> argmax = 0 -> dst0[0]
            else {
                unsigned j = ~(unsigned)(key & 0xFFFFFFFFull);
                nxt = dstA[j];
            }
            astorei(&p.nxt[base + t], nxt);
        }
    }
    gbar(p.ctr, 5 * NBLK);

    // ================= block 0: binary lifting next^4096 =================
    if (b == 0) {
        for (int i = t; i < N_NODES; i += NTHR) A[i] = aloadi(&p.nxt[i]);
        __syncthreads();
        for (int r = 0; r < 12; ++r) {        // 2^12 = 4096 steps
            for (int i = t; i < N_NODES; i += NTHR) B[i] = A[A[i]];
            __syncthreads();
            for (int i = t; i < N_NODES; i += NTHR) A[i] = B[i];
            __syncthreads();
        }
        if (t == 0) {
            u64 ak = ald64(p.argkey);
            int start = (int)~(unsigned)(ak & 0xFFFFFFFFull);
            p.out[N_NODES] = (float)A[start];
        }
    }
}

// ---------- launch ----------

extern "C" void kernel_launch(void* const* d_in, const int* in_sizes, int n_in,
                              void* d_out, int out_size, void* d_ws, size_t ws_size,
                              hipStream_t stream) {
    Params p;
    p.x    = (const float*)d_in[0];
    p.ei   = (const int*)  d_in[1];
    p.W1   = (const float*)d_in[2];
    p.as1  = (const float*)d_in[3];
    p.ad1  = (const float*)d_in[4];
    p.b1   = (const float*)d_in[5];
    p.W2   = (const float*)d_in[6];
    p.as2  = (const float*)d_in[7];
    p.ad2  = (const float*)d_in[8];
    p.b2   = (const float*)d_in[9];
    p.W3   = (const float*)d_in[10];
    p.as3  = (const float*)d_in[11];
    p.ad3  = (const float*)d_in[12];
    p.b3   = (const float*)d_in[13];
    p.phi1 = (const float*)d_in[14];
    p.phi2 = (const float*)d_in[15];
    p.out  = (float*)d_out;

    char* ws = (char*)d_ws;
    p.P2     = (u64*)(ws + 0);          // 64 KB
    p.P3     = (u64*)(ws + 65536);      // 32 KB
    p.xf     = (float*)(ws + 98304);    // 16 KB
    p.nxt    = (int*)(ws + 114688);     // 16 KB
    p.scalS  = (float*)(ws + 131072);
    p.argkey = (u64*)(ws + 131072 + 8);
    p.ctr    = (unsigned*)(ws + 131072 + 16);

    // zero only the scalar/counter block (barrier counter cannot self-init)
    hipMemsetAsync((void*)(ws + 131072), 0, 256, stream);
    k_gat<<<dim3(NBLK), dim3(NTHR), 0, stream>>>(p);
}

// Round 6
// 181.118 us; speedup vs baseline: 3.3105x; 1.2631x over previous
//
#include <hip/hip_runtime.h>
#include <math.h>

#define N_NODES 4096
#define E_EDGES 131072
#define NEG_SLOPE 0.2f
#define NBLK 256
#define NTHR 512
#define SLICE 16                 // N_NODES / NBLK
#define CHUNK 512                // E_EDGES / NBLK
#define CAP 768                  // bucket capacity per slice (mean 512, sigma ~22.6)

typedef unsigned long long u64;
typedef unsigned u32;

#define SCOPE_A __HIP_MEMORY_SCOPE_AGENT
#define RLX __ATOMIC_RELAXED

// ---------- agent-scope (coherence-point) helpers ----------
__device__ __forceinline__ float aloadf(const float* p) { return __hip_atomic_load(p, RLX, SCOPE_A); }
__device__ __forceinline__ void astoref(float* p, float v) { __hip_atomic_store(p, v, RLX, SCOPE_A); }
__device__ __forceinline__ int aloadi(const int* p) { return __hip_atomic_load(p, RLX, SCOPE_A); }
__device__ __forceinline__ void astorei(int* p, int v) { __hip_atomic_store(p, v, RLX, SCOPE_A); }
__device__ __forceinline__ u32 ald32(const u32* p) { return __hip_atomic_load(p, RLX, SCOPE_A); }
__device__ __forceinline__ void ast32(u32* p, u32 v) { __hip_atomic_store(p, v, RLX, SCOPE_A); }
__device__ __forceinline__ u64 ald64(const u64* p) { return __hip_atomic_load(p, RLX, SCOPE_A); }
__device__ __forceinline__ void ast64(u64* p, u64 v) { __hip_atomic_store(p, v, RLX, SCOPE_A); }
__device__ __forceinline__ void aaddf(float* p, float v) { __hip_atomic_fetch_add(p, v, RLX, SCOPE_A); }
__device__ __forceinline__ void amax64(u64* p, u64 v) { __hip_atomic_fetch_max(p, v, RLX, SCOPE_A); }

union F2U { float2 f; u64 u; };
__device__ __forceinline__ u64 packf2(float a, float b) { F2U x; x.f = make_float2(a, b); return x.u; }
__device__ __forceinline__ float2 unpackf2(u64 v) { F2U x; x.u = v; return x.f; }

// order-preserving float->uint encoding (packed 64-bit argmax keys)
__device__ __forceinline__ unsigned enc_f(float f) {
    unsigned u = __float_as_uint(f);
    return (u & 0x80000000u) ? ~u : (u | 0x80000000u);
}
__device__ __forceinline__ float lrelu(float x) { return x >= 0.0f ? x : NEG_SLOPE * x; }

// Relaxed grid barrier (validated R4/R5): all cross-block data moves via
// agent-scope ops; waitcnt drains this wave's traffic before arrival.
__device__ __forceinline__ void gbar(unsigned* ctr, unsigned target) {
    __builtin_amdgcn_s_waitcnt(0);
    __syncthreads();
    if (threadIdx.x == 0) {
        __hip_atomic_fetch_add(ctr, 1u, RLX, SCOPE_A);
        while (__hip_atomic_load(ctr, RLX, SCOPE_A) < target)
            __builtin_amdgcn_s_sleep(2);
    }
    __syncthreads();
}

struct Params {
    const float* x; const int* ei;
    const float* W1; const float* as1; const float* ad1; const float* b1;
    const float* W2; const float* as2; const float* ad2; const float* b2;
    const float* W3; const float* as3; const float* ad3; const float* b3;
    const float* phi1; const float* phi2;
    float* out;
    u32* cnt_d; u32* cnt_s;     // [producer_block][slice] counts
    u32* pos_d; u32* pos_s;     // [producer_block][slice] scatter bases
    u32* bucket_d;              // 256*CAP recs: src | li<<12
    u32* bucket_s;              // 256*CAP recs: j | li<<17
    u64* P2;                    // per-node (es2,z0 | z1,z2)
    u64* P3;                    // per-node (es3,z3)
    float* xf;                  // per-node softmax value
    int* nxt;                   // per-node chain successor
    float* scalS;               // softmax denominator
    u64* argkey;                // global argmax(xf) packed key
    unsigned* ctr;              // barrier counter
};

__global__ __launch_bounds__(NTHR) void k_gat(Params p) {
    const int t = threadIdx.x;
    const int b = blockIdx.x;
    const int base = b * SLICE;
    const int j0 = b * CHUNK;

    __shared__ u32 h[2][256];        // histogram, then scatter cursors
    __shared__ u32 scn[2][256];      // prefix scan
    __shared__ u32 s_tot[2];         // own-slice totals [0]=dst-bucket, [1]=src-bucket
    __shared__ float s_ssum[SLICE];
    __shared__ float s_acc[SLICE][3];
    __shared__ float s_ed[SLICE];
    __shared__ float s_es[SLICE];
    __shared__ float s_z[SLICE][3];
    __shared__ float s_exp[SLICE];
    __shared__ float s_xf[SLICE];
    __shared__ u64   s_key[SLICE];
    __shared__ float s_phired[128];
    __shared__ float s_p12;
    __shared__ int A[N_NODES];
    __shared__ int B[N_NODES];

    const int* srcA = p.ei;
    const int* dstA = p.ei + E_EDGES;
    const int lane = t & 255, row = t >> 8;   // for the dual prefix scan

    // ===== P0: histogram own contiguous 512-edge chunk (by dst-slice and src-slice)
    {
        if (t < 256) { h[0][t] = 0; h[1][t] = 0; }
        __syncthreads();
        {
            int j = j0 + t;          // CHUNK == NTHR
            int s = srcA[j], d = dstA[j];
            atomicAdd(&h[0][d >> 4], 1u);
            atomicAdd(&h[1][s >> 4], 1u);
        }
        __syncthreads();
        if (t < 256)      ast32(&p.cnt_d[b * 256 + t], h[0][t]);
        else              ast32(&p.cnt_s[b * 256 + (t - 256)], h[1][t - 256]);
    }
    gbar(p.ctr, 1 * NBLK);

    // ===== P1: per-slice exclusive prefix over producer blocks -> scatter bases
    {
        const u32* cnt = (row == 0) ? p.cnt_d : p.cnt_s;
        u32 c = ald32(&cnt[lane * 256 + b]);
        scn[row][lane] = c;
        __syncthreads();
#pragma unroll
        for (int o = 1; o < 256; o <<= 1) {
            u32 v = (lane >= o) ? scn[row][lane - o] : 0u;
            __syncthreads();
            scn[row][lane] += v;
            __syncthreads();
        }
        u32 excl = scn[row][lane] - c;
        u32* pos = (row == 0) ? p.pos_d : p.pos_s;
        ast32(&pos[lane * 256 + b], (u32)b * CAP + excl);
        if (lane == 255) s_tot[row] = scn[row][255];
        __syncthreads();
    }
    gbar(p.ctr, 2 * NBLK);

    // ===== P2: scatter own chunk into both bucket arrays
    {
        if (t < 256) h[0][t] = ald32(&p.pos_d[b * 256 + t]);
        else         h[1][t - 256] = ald32(&p.pos_s[b * 256 + (t - 256)]);
        __syncthreads();
        {
            int j = j0 + t;
            int s = srcA[j], d = dstA[j];
            u32 slotD = atomicAdd(&h[0][d >> 4], 1u);
            ast32(&p.bucket_d[slotD], (u32)s | ((u32)(d & 15) << 12));
            u32 slotS = atomicAdd(&h[1][s >> 4], 1u);
            ast32(&p.bucket_s[slotS], (u32)j | ((u32)(s & 15) << 17));
        }
    }
    gbar(p.ctr, 3 * NBLK);

    // ===== L1: layer-1 over own dst-bucket (h = x)
    {
        float w0 = p.W1[0], w1 = p.W1[1], w2 = p.W1[2];
        float cs = w0 * p.as1[0] + w1 * p.as1[1] + w2 * p.as1[2];
        float cd = w0 * p.ad1[0] + w1 * p.ad1[1] + w2 * p.ad1[2];
        if (t < SLICE) {
            float xi = p.x[base + t];
            s_ed[t] = xi * cd;
            s_ssum[t] = 0.0f;
            s_acc[t][0] = 0.0f; s_acc[t][1] = 0.0f; s_acc[t][2] = 0.0f;
        }
        __syncthreads();
        if (t < SLICE) {             // self-loop
            float xi = p.x[base + t];
            float w = expf(lrelu(xi * cs + s_ed[t]));
            atomicAdd(&s_ssum[t], w);
            atomicAdd(&s_acc[t][0], w * (xi * w0));
            atomicAdd(&s_acc[t][1], w * (xi * w1));
            atomicAdd(&s_acc[t][2], w * (xi * w2));
        }
        u32 n = s_tot[0];
        for (u32 r = t; r < n; r += NTHR) {
            u32 rec = ald32(&p.bucket_d[b * CAP + r]);
            int s = rec & 0xFFF, li = (rec >> 12) & 15;
            float xs = p.x[s];
            float w = expf(lrelu(xs * cs + s_ed[li]));
            atomicAdd(&s_ssum[li], w);
            atomicAdd(&s_acc[li][0], w * (xs * w0));
            atomicAdd(&s_acc[li][1], w * (xs * w1));
            atomicAdd(&s_acc[li][2], w * (xs * w2));
        }
        __syncthreads();
        if (t < SLICE) {             // epilogue -> publish P2
            int i = base + t;
            float inv = 1.0f / (s_ssum[t] + 1e-16f);
            float h0 = s_acc[t][0] * inv + p.b1[0]; h0 = h0 > 0.0f ? h0 : 0.0f;
            float h1 = s_acc[t][1] * inv + p.b1[1]; h1 = h1 > 0.0f ? h1 : 0.0f;
            float h2 = s_acc[t][2] * inv + p.b1[2]; h2 = h2 > 0.0f ? h2 : 0.0f;
            float z0 = h0 * p.W2[0] + h1 * p.W2[1] + h2 * p.W2[2];
            float z1 = h0 * p.W2[3] + h1 * p.W2[4] + h2 * p.W2[5];
            float z2 = h0 * p.W2[6] + h1 * p.W2[7] + h2 * p.W2[8];
            float es2 = z0 * p.as2[0] + z1 * p.as2[1] + z2 * p.as2[2];
            float ed2 = z0 * p.ad2[0] + z1 * p.ad2[1] + z2 * p.ad2[2];
            ast64(&p.P2[i * 2 + 0], packf2(es2, z0));
            ast64(&p.P2[i * 2 + 1], packf2(z1, z2));
            s_es[t] = es2; s_ed[t] = ed2;
            s_z[t][0] = z0; s_z[t][1] = z1; s_z[t][2] = z2;
            s_ssum[t] = 0.0f;
            s_acc[t][0] = 0.0f; s_acc[t][1] = 0.0f; s_acc[t][2] = 0.0f;
        }
    }
    gbar(p.ctr, 4 * NBLK);

    // ===== L2: layer-2 over own dst-bucket
    {
        if (t < SLICE) {             // self-loop
            float w = expf(lrelu(s_es[t] + s_ed[t]));
            atomicAdd(&s_ssum[t], w);
            atomicAdd(&s_acc[t][0], w * s_z[t][0]);
            atomicAdd(&s_acc[t][1], w * s_z[t][1]);
            atomicAdd(&s_acc[t][2], w * s_z[t][2]);
        }
        u32 n = s_tot[0];
        for (u32 r = t; r < n; r += NTHR) {
            u32 rec = ald32(&p.bucket_d[b * CAP + r]);
            int s = rec & 0xFFF, li = (rec >> 12) & 15;
            float2 f0 = unpackf2(ald64(&p.P2[s * 2 + 0]));
            float2 f1 = unpackf2(ald64(&p.P2[s * 2 + 1]));
            float w = expf(lrelu(f0.x + s_ed[li]));
            atomicAdd(&s_ssum[li], w);
            atomicAdd(&s_acc[li][0], w * f0.y);
            atomicAdd(&s_acc[li][1], w * f1.x);
            atomicAdd(&s_acc[li][2], w * f1.y);
        }
        __syncthreads();
        if (t < SLICE) {             // epilogue -> publish P3
            int i = base + t;
            float inv = 1.0f / (s_ssum[t] + 1e-16f);
            float h0 = s_acc[t][0] * inv + p.b2[0]; h0 = h0 > 0.0f ? h0 : 0.0f;
            float h1 = s_acc[t][1] * inv + p.b2[1]; h1 = h1 > 0.0f ? h1 : 0.0f;
            float h2 = s_acc[t][2] * inv + p.b2[2]; h2 = h2 > 0.0f ? h2 : 0.0f;
            float z3 = h0 * p.W3[0] + h1 * p.W3[1] + h2 * p.W3[2];
            float es3 = z3 * p.as3[0];
            float ed3 = z3 * p.ad3[0];
            ast64(&p.P3[i], packf2(es3, z3));
            s_es[t] = es3; s_ed[t] = ed3; s_z[t][0] = z3;
            s_ssum[t] = 0.0f; s_acc[t][0] = 0.0f;
        }
    }
    gbar(p.ctr, 5 * NBLK);

    // ===== L3: layer-3 over own dst-bucket + softmax denominator + p12
    {
        if (t < SLICE) {             // self-loop
            float w = expf(lrelu(s_es[t] + s_ed[t]));
            atomicAdd(&s_ssum[t], w);
            atomicAdd(&s_acc[t][0], w * s_z[t][0]);
        }
        u32 n = s_tot[0];
        for (u32 r = t; r < n; r += NTHR) {
            u32 rec = ald32(&p.bucket_d[b * CAP + r]);
            int s = rec & 0xFFF, li = (rec >> 12) & 15;
            float2 f = unpackf2(ald64(&p.P3[s]));
            float w = expf(lrelu(f.x + s_ed[li]));
            atomicAdd(&s_ssum[li], w);
            atomicAdd(&s_acc[li][0], w * f.y);
        }
        __syncthreads();
        if (t < SLICE) {
            float x3 = s_acc[t][0] / (s_ssum[t] + 1e-16f) + p.b3[0];
            s_exp[t] = expf(x3);
        }
        if (t < 128) s_phired[t] = p.phi1[t] * p.phi2[t];
        __syncthreads();
        if (t < 64) s_phired[t] += s_phired[t + 64];
        __syncthreads();
        if (t == 0) {
            float a = 0.0f;
            for (int k = 0; k < 64; ++k) a += s_phired[k];
            s_p12 = a;
            float part = 0.0f;
            for (int k = 0; k < SLICE; ++k) part += s_exp[k];
            aaddf(p.scalS, part);
        }
    }
    gbar(p.ctr, 6 * NBLK);

    // ===== softmax write + global argmax
    {
        float S = aloadf(p.scalS);
        if (t < SLICE) {
            float v = s_exp[t] / S;
            s_xf[t] = v;
            astoref(&p.xf[base + t], v);
            p.out[base + t] = v;
            s_key[t] = 0ull;
        }
        __syncthreads();
        if (t == 0) {
            float bv = -INFINITY; int bi = 0;
            for (int k = 0; k < SLICE; ++k) {
                float v = s_xf[k];
                if (v > bv) { bv = v; bi = base + k; }   // ascending k -> first-index ties
            }
            u64 key = ((u64)enc_f(bv) << 32) | (u64)(~(unsigned)bi);
            amax64(p.argkey, key);
        }
    }
    gbar(p.ctr, 7 * NBLK);

    // ===== chain: own src-bucket argmax of tanh score
    {
        float p12 = s_p12;
        const float scale = 1.0f / 11.313708498984761f;   // 1/sqrt(128)
        u32 n = s_tot[1];
        for (u32 r = t; r < n; r += NTHR) {
            u32 rec = ald32(&p.bucket_s[b * CAP + r]);
            u32 j = rec & 0x1FFFFu;
            int li = (int)(rec >> 17);
            int d = dstA[j];
            float xfd = aloadf(&p.xf[d]);
            float sc = tanhf(((p12 * s_xf[li]) * xfd) * scale);
            u64 key = ((u64)enc_f(sc) << 32) | (u64)(~j);
            atomicMax(&s_key[li], key);
        }
        __syncthreads();
        if (t < SLICE) {
            u64 key = s_key[t];
            int nxt;
            if (key == 0ull) nxt = dstA[0];   // all -inf -> argmax = 0 -> dst0[0]
            else {
                unsigned j = ~(unsigned)(key & 0xFFFFFFFFull);
                nxt = dstA[j];
            }
            astorei(&p.nxt[base + t], nxt);
        }
    }
    gbar(p.ctr, 8 * NBLK);

    // ===== block 0: binary lifting next^4096
    if (b == 0) {
        for (int i = t; i < N_NODES; i += NTHR) A[i] = aloadi(&p.nxt[i]);
        __syncthreads();
        for (int r = 0; r < 12; ++r) {        // 2^12 = 4096 steps
            for (int i = t; i < N_NODES; i += NTHR) B[i] = A[A[i]];
            __syncthreads();
            for (int i = t; i < N_NODES; i += NTHR) A[i] = B[i];
            __syncthreads();
        }
        if (t == 0) {
            u64 ak = ald64(p.argkey);
            int start = (int)~(unsigned)(ak & 0xFFFFFFFFull);
            p.out[N_NODES] = (float)A[start];
        }
    }
}

// ---------- launch ----------

extern "C" void kernel_launch(void* const* d_in, const int* in_sizes, int n_in,
                              void* d_out, int out_size, void* d_ws, size_t ws_size,
                              hipStream_t stream) {
    Params p;
    p.x    = (const float*)d_in[0];
    p.ei   = (const int*)  d_in[1];
    p.W1   = (const float*)d_in[2];
    p.as1  = (const float*)d_in[3];
    p.ad1  = (const float*)d_in[4];
    p.b1   = (const float*)d_in[5];
    p.W2   = (const float*)d_in[6];
    p.as2  = (const float*)d_in[7];
    p.ad2  = (const float*)d_in[8];
    p.b2   = (const float*)d_in[9];
    p.W3   = (const float*)d_in[10];
    p.as3  = (const float*)d_in[11];
    p.ad3  = (const float*)d_in[12];
    p.b3   = (const float*)d_in[13];
    p.phi1 = (const float*)d_in[14];
    p.phi2 = (const float*)d_in[15];
    p.out  = (float*)d_out;

    char* ws = (char*)d_ws;
    size_t off = 0;
    p.cnt_d    = (u32*)(ws + off); off += 256 * 256 * 4;       // 256 KB
    p.cnt_s    = (u32*)(ws + off); off += 256 * 256 * 4;
    p.pos_d    = (u32*)(ws + off); off += 256 * 256 * 4;
    p.pos_s    = (u32*)(ws + off); off += 256 * 256 * 4;
    p.bucket_d = (u32*)(ws + off); off += 256 * CAP * 4;       // 768 KB
    p.bucket_s = (u32*)(ws + off); off += 256 * CAP * 4;
    p.P2       = (u64*)(ws + off); off += N_NODES * 16;        // 64 KB
    p.P3       = (u64*)(ws + off); off += N_NODES * 8;         // 32 KB
    p.xf       = (float*)(ws + off); off += N_NODES * 4;
    p.nxt      = (int*)(ws + off); off += N_NODES * 4;
    char* scalblk = ws + off;
    p.scalS    = (float*)scalblk;
    p.argkey   = (u64*)(scalblk + 8);
    p.ctr      = (unsigned*)(scalblk + 16);

    // zero only the scalar/counter block (barrier counter cannot self-init)
    hipMemsetAsync((void*)scalblk, 0, 256, stream);
    k_gat<<<dim3(NBLK), dim3(NTHR), 0, stream>>>(p);
}